// Round 13
// baseline (453.198 us; speedup 1.0000x reference)
//
#include <hip/hip_runtime.h>
#include <math.h>

#define TLEN 512
#define NB   1024
#define HSTR 80                 // h buf row stride (f16): 40 dwords -> <=2-way
#define HLAY (2 * HSTR)         // 2 batch rows per parity
#define XCH  64                 // timesteps per x chunk
#define XBSTR (XCH * 32 + 16)   // per-batch chunk stride (f16): 1032 dwords = 8 mod 32
#define XHALF (2 * XBSTR)       // one chunk buffer (2 batches)

#define NLOG2E  (-1.44269504f)  // -log2(e): sigmoid gates
#define N2LOG2E (-2.88539008f)  // -2log2(e): tanh gate / tanh(c)

typedef _Float16 f16;
typedef f16   f16x4 __attribute__((ext_vector_type(4)));
typedef f16   f16x8 __attribute__((ext_vector_type(8)));
typedef float f32x4 __attribute__((ext_vector_type(4)));

__device__ __forceinline__ float ex2(float x) {
#if __has_builtin(__builtin_amdgcn_exp2f)
    return __builtin_amdgcn_exp2f(x);
#else
    return exp2f(x);
#endif
}
__device__ __forceinline__ float rcp_(float x) { return __builtin_amdgcn_rcpf(x); }
__device__ __forceinline__ float sel4(f32x4 v, int g) {
    float a = (g & 1) ? v[1] : v[0];
    float b = (g & 1) ? v[3] : v[2];
    return (g & 2) ? b : a;
}

// 512 blocks x 512 threads -> target 2 blocks/CU (4 waves/SIMD): two
// independent phase pipelines per CU interleave and hide each other's latency
// chains. launch_bounds(512,2) keeps the VGPR budget at the 256 tier so the
// ~92-VGPR body does NOT spill (R12's (512,4) capped at 64 -> scratch spills,
// 47 MB of writes, 1.8x regression); HW still co-schedules 2 blocks since
// 92 <= 128 and LDS ~18 KB.
// Block owns 2 batches. Waves 0-3 = layer 0 (step it), waves 4-7 = layer 1
// (step it-1), R9's 1-barrier-per-phase pipeline. MFMA cols: 2 real batches
// duplicated x8 (b_own = bc&1); copy-group G=(bc>>1)&3 picks the acc reg ->
// each lane owns ONE (hidden,batch) cell in registers (writes gated to bc<8).
__global__ __launch_bounds__(512, 2) void lstm_fused(
    const float* __restrict__ x,
    const float* __restrict__ Wih0, const float* __restrict__ Whh0,
    const float* __restrict__ bih0, const float* __restrict__ bhh0,
    const float* __restrict__ Wih1, const float* __restrict__ Whh1,
    const float* __restrict__ bih1, const float* __restrict__ bhh1,
    const float* __restrict__ fc1w, const float* __restrict__ fc1b,
    const float* __restrict__ fc2w, const float* __restrict__ fc2b,
    float* __restrict__ out)
{
    __shared__ __align__(16) f16 x_lds[2 * XHALF];    // ~16.5 KB
    __shared__ __align__(16) f16 h1buf[2 * HLAY];
    __shared__ __align__(16) f16 h2buf[2 * HLAY];
    __shared__ float zbuf[2][33];

    const int tid   = threadIdx.x;
    const int lane  = tid & 63;
    const int w     = tid >> 6;          // 0..7
    const int wg    = w & 3;             // hidden group within layer
    const bool isL0 = (w < 4);
    const int bc    = lane & 15;         // MFMA col / A-row-in-tile
    const int lq    = lane >> 4;         // k-octet / D-row quad
    const int G     = (bc >> 1) & 3;     // acc reg this lane consumes
    const int b_own = bc & 1;            // batch this lane's column carries
    const int bg0   = blockIdx.x * 2;

    // ---- one-time: pre-scaled A-fragments + bias C-init vectors ----
    const float wsc[4] = {NLOG2E, NLOG2E, N2LOG2E, NLOG2E};
    f16x8 A[4][4];
    f32x4 cb[4];
    #pragma unroll
    for (int g = 0; g < 4; ++g) {
        const int gr = g * 64 + 16 * wg + bc;
        #pragma unroll
        for (int s = 0; s < 4; ++s) {
            #pragma unroll
            for (int i = 0; i < 8; ++i) {
                int k = 32 * s + lq * 8 + i;
                float v = 0.0f;
                if (isL0) {
                    if (s < 3) v = (k < 32) ? Wih0[gr * 32 + k] : Whh0[gr * 64 + (k - 32)];
                } else {
                    v = (k < 64) ? Wih1[gr * 64 + k] : Whh1[gr * 64 + (k - 64)];
                }
                A[g][s][i] = (f16)(v * wsc[g]);
            }
        }
        #pragma unroll
        for (int r = 0; r < 4; ++r) {
            const int gd = g * 64 + 16 * wg + 4 * lq + r;
            float bb = isL0 ? (bih0[gd] + bhh0[gd]) : (bih1[gd] + bhh1[gd]);
            cb[g][r] = bb * wsc[g];
        }
    }

    // ---- zero h LDS ----
    for (int i = tid; i < 2 * HLAY; i += 512) { h1buf[i] = (f16)0; h2buf[i] = (f16)0; }

    // ---- chunk refill: timesteps [64ch,64ch+64) of 2 batches, all 512 thr ----
    const int rf_b   = tid >> 8;         // 0..1
    const int rf_rem = tid & 255;
#define REFILL(ch)                                                            \
    {                                                                         \
        f16* dst = x_lds + ((ch) & 1) * XHALF + rf_b * XBSTR;                 \
        const float4* src = (const float4*)(x +                               \
            ((long)(bg0 + rf_b) * TLEN + (ch) * XCH) * 32);                   \
        _Pragma("unroll")                                                     \
        for (int j = 0; j < 2; ++j) {                                         \
            float4 v = src[rf_rem + 256 * j];                                 \
            f16x4 hv;                                                         \
            hv[0]=(f16)v.x; hv[1]=(f16)v.y; hv[2]=(f16)v.z; hv[3]=(f16)v.w;   \
            *(f16x4*)(dst + (rf_rem + 256 * j) * 4) = hv;                     \
        }                                                                     \
    }

    REFILL(0)                       // chunk 0 -> parity 0
    __syncthreads();

    const int bch = b_own * HSTR + lq * 8;                 // broadcast h B-frag offset
    const int bxx = b_own * XBSTR + lq * 8;                // x B-frag offset
    const int hwr = b_own * HSTR + 16 * wg + 4 * lq + G;   // h write (bc<8 only)

    float cst = 0.0f;   // cell state of my (16wg+4lq+G, b_own)

#define CELL_UPDATE(HBUF, PW)                                                 \
    {                                                                         \
        float pi = sel4(a0, G);                                               \
        float pf = sel4(a1, G);                                               \
        float pg = sel4(a2, G);                                               \
        float po = sel4(a3, G);                                               \
        float iv = rcp_(1.0f + ex2(pi));                                      \
        float fv = rcp_(1.0f + ex2(pf));                                      \
        float gv = fmaf(2.0f, rcp_(1.0f + ex2(pg)), -1.0f);                   \
        float ov = rcp_(1.0f + ex2(po));                                      \
        cst = fmaf(fv, cst, iv * gv);                                         \
        float tc = fmaf(2.0f, rcp_(1.0f + ex2(cst * N2LOG2E)), -1.0f);        \
        if (bc < 8) HBUF[(PW) * HLAY + hwr] = (f16)(ov * tc);                 \
    }

// L0 at iteration it (parity p = it&1): reads x_lds chunk (it>>6), h1buf[p^1];
// writes h1buf[p].
#define L0_PHASE(p, itv)                                                      \
    {                                                                         \
        f16x8 b0 = *(const f16x8*)(x_lds + (((itv) >> 6) & 1) * XHALF +       \
                                   ((itv) & 63) * 32 + bxx);                  \
        f16x8 b1 = *(const f16x8*)(h1buf + ((p)^1) * HLAY + bch);             \
        f16x8 b2 = *(const f16x8*)(h1buf + ((p)^1) * HLAY + bch + 32);        \
        __builtin_amdgcn_s_setprio(1);                                        \
        f32x4 a0 = __builtin_amdgcn_mfma_f32_16x16x32_f16(A[0][0], b0, cb[0], 0,0,0); \
        f32x4 a1 = __builtin_amdgcn_mfma_f32_16x16x32_f16(A[1][0], b0, cb[1], 0,0,0); \
        f32x4 a2 = __builtin_amdgcn_mfma_f32_16x16x32_f16(A[2][0], b0, cb[2], 0,0,0); \
        f32x4 a3 = __builtin_amdgcn_mfma_f32_16x16x32_f16(A[3][0], b0, cb[3], 0,0,0); \
        a0 = __builtin_amdgcn_mfma_f32_16x16x32_f16(A[0][1], b1, a0, 0,0,0);  \
        a1 = __builtin_amdgcn_mfma_f32_16x16x32_f16(A[1][1], b1, a1, 0,0,0);  \
        a2 = __builtin_amdgcn_mfma_f32_16x16x32_f16(A[2][1], b1, a2, 0,0,0);  \
        a3 = __builtin_amdgcn_mfma_f32_16x16x32_f16(A[3][1], b1, a3, 0,0,0);  \
        a0 = __builtin_amdgcn_mfma_f32_16x16x32_f16(A[0][2], b2, a0, 0,0,0);  \
        a1 = __builtin_amdgcn_mfma_f32_16x16x32_f16(A[1][2], b2, a1, 0,0,0);  \
        a2 = __builtin_amdgcn_mfma_f32_16x16x32_f16(A[2][2], b2, a2, 0,0,0);  \
        a3 = __builtin_amdgcn_mfma_f32_16x16x32_f16(A[3][2], b2, a3, 0,0,0);  \
        __builtin_amdgcn_s_setprio(0);                                        \
        CELL_UPDATE(h1buf, p)                                                 \
    }

// L1 at iteration it (t = it-1, p = it&1): reads h1buf[p^1] (=h1[t]),
// h2buf[p] (=h2[t-1]); writes h2buf[p^1] (=h2[t]).
#define L1_PHASE(p)                                                           \
    {                                                                         \
        f16x8 b0 = *(const f16x8*)(h1buf + ((p)^1) * HLAY + bch);             \
        f16x8 b1 = *(const f16x8*)(h1buf + ((p)^1) * HLAY + bch + 32);        \
        f16x8 b2 = *(const f16x8*)(h2buf + (p) * HLAY + bch);                 \
        f16x8 b3 = *(const f16x8*)(h2buf + (p) * HLAY + bch + 32);            \
        __builtin_amdgcn_s_setprio(1);                                        \
        f32x4 a0 = __builtin_amdgcn_mfma_f32_16x16x32_f16(A[0][0], b0, cb[0], 0,0,0); \
        f32x4 a1 = __builtin_amdgcn_mfma_f32_16x16x32_f16(A[1][0], b0, cb[1], 0,0,0); \
        f32x4 a2 = __builtin_amdgcn_mfma_f32_16x16x32_f16(A[2][0], b0, cb[2], 0,0,0); \
        f32x4 a3 = __builtin_amdgcn_mfma_f32_16x16x32_f16(A[3][0], b0, cb[3], 0,0,0); \
        a0 = __builtin_amdgcn_mfma_f32_16x16x32_f16(A[0][1], b1, a0, 0,0,0);  \
        a1 = __builtin_amdgcn_mfma_f32_16x16x32_f16(A[1][1], b1, a1, 0,0,0);  \
        a2 = __builtin_amdgcn_mfma_f32_16x16x32_f16(A[2][1], b1, a2, 0,0,0);  \
        a3 = __builtin_amdgcn_mfma_f32_16x16x32_f16(A[3][1], b1, a3, 0,0,0);  \
        a0 = __builtin_amdgcn_mfma_f32_16x16x32_f16(A[0][2], b2, a0, 0,0,0);  \
        a1 = __builtin_amdgcn_mfma_f32_16x16x32_f16(A[1][2], b2, a1, 0,0,0);  \
        a2 = __builtin_amdgcn_mfma_f32_16x16x32_f16(A[2][2], b2, a2, 0,0,0);  \
        a3 = __builtin_amdgcn_mfma_f32_16x16x32_f16(A[3][2], b2, a3, 0,0,0);  \
        a0 = __builtin_amdgcn_mfma_f32_16x16x32_f16(A[0][3], b3, a0, 0,0,0);  \
        a1 = __builtin_amdgcn_mfma_f32_16x16x32_f16(A[1][3], b3, a1, 0,0,0);  \
        a2 = __builtin_amdgcn_mfma_f32_16x16x32_f16(A[2][3], b3, a2, 0,0,0);  \
        a3 = __builtin_amdgcn_mfma_f32_16x16x32_f16(A[3][3], b3, a3, 0,0,0);  \
        __builtin_amdgcn_s_setprio(0);                                        \
        CELL_UPDATE(h2buf, (p)^1)                                             \
    }

    // ---- pipeline: it = 0 .. 512 ----
    if (isL0) L0_PHASE(0, 0)            // it = 0
    REFILL(1)                           // chunk 1 -> parity 1 (reads start at it=64)
    __syncthreads();

    #pragma unroll 1
    for (int k = 0; k < 255; ++k) {     // it = 2k+1, 2k+2  (1..510)
        if (isL0) L0_PHASE(1, 2 * k + 1) else L1_PHASE(1)
        __syncthreads();
        const int it2 = 2 * k + 2;
        if (isL0) L0_PHASE(0, it2) else L1_PHASE(0)
        if ((it2 & (XCH - 1)) == 0 && it2 <= TLEN - 2 * XCH)
            REFILL((it2 >> 6) + 1)      // chunk c+1 at it=64c (c=1..6)
        __syncthreads();
    }

    if (isL0) L0_PHASE(1, 511) else L1_PHASE(1)   // it = 511
    __syncthreads();
    if (!isL0) L1_PHASE(0)                        // it = 512 (L1 finishes h2[511])
    __syncthreads();

#undef L0_PHASE
#undef L1_PHASE
#undef CELL_UPDATE
#undef REFILL

    // ---- FC head: h2[511] is in parity 1 ----
    const f16* h2f = h2buf + HLAY;
    if (tid < 64) {
        int b = tid >> 5, m = tid & 31;
        float z = fc1b[m];
        #pragma unroll
        for (int j = 0; j < 64; ++j)
            z = fmaf(fc1w[m * 64 + j], (float)h2f[b * HSTR + j], z);
        zbuf[b][m] = fmaxf(z, 0.0f);
    }
    __syncthreads();
    if (tid < 4) {
        int b = tid >> 1, o = tid & 1;
        float s = fc2b[o];
        #pragma unroll
        for (int m = 0; m < 32; ++m)
            s = fmaf(fc2w[o * 32 + m], zbuf[b][m], s);
        out[(long)(bg0 + b) * 2 + o] = s;
    }
}

extern "C" void kernel_launch(void* const* d_in, const int* in_sizes, int n_in,
                              void* d_out, int out_size, void* d_ws, size_t ws_size,
                              hipStream_t stream) {
    const float* x    = (const float*)d_in[0];
    const float* Wih0 = (const float*)d_in[1];
    const float* Whh0 = (const float*)d_in[2];
    const float* bih0 = (const float*)d_in[3];
    const float* bhh0 = (const float*)d_in[4];
    const float* Wih1 = (const float*)d_in[5];
    const float* Whh1 = (const float*)d_in[6];
    const float* bih1 = (const float*)d_in[7];
    const float* bhh1 = (const float*)d_in[8];
    const float* fc1w = (const float*)d_in[9];
    const float* fc1b = (const float*)d_in[10];
    const float* fc2w = (const float*)d_in[11];
    const float* fc2b = (const float*)d_in[12];
    float* out = (float*)d_out;

    lstm_fused<<<dim3(NB / 2), dim3(512), 0, stream>>>(
        x, Wih0, Whh0, bih0, bhh0, Wih1, Whh1, bih1, bhh1,
        fc1w, fc1b, fc2w, fc2b, out);
}

// Round 14
// 412.655 us; speedup vs baseline: 1.0982x; 1.0982x over previous
//
#include <hip/hip_runtime.h>
#include <math.h>

#define TLEN 512
#define NB   1024
#define HSTR 80                 // h buf row stride (f16): 40 dwords -> <=2-way
#define HLAY (4 * HSTR)         // 4 batch rows per parity
#define XCH  64                 // timesteps per x chunk
#define XBSTR (XCH * 32 + 16)   // per-batch chunk stride (f16)
#define XHALF (4 * XBSTR)       // one chunk buffer (4 batches)

#define NLOG2E  (-1.44269504f)  // -log2(e): sigmoid gates
#define N2LOG2E (-2.88539008f)  // -2log2(e): tanh gate / tanh(c)

typedef _Float16 f16;
typedef f16   f16x4 __attribute__((ext_vector_type(4)));
typedef f16   f16x8 __attribute__((ext_vector_type(8)));
typedef float f32x4 __attribute__((ext_vector_type(4)));

__device__ __forceinline__ float ex2(float x) {
#if __has_builtin(__builtin_amdgcn_exp2f)
    return __builtin_amdgcn_exp2f(x);
#else
    return exp2f(x);
#endif
}
__device__ __forceinline__ float rcp_(float x) { return __builtin_amdgcn_rcpf(x); }
__device__ __forceinline__ float sel4(f32x4 v, int g) {
    float a = (g & 1) ? v[1] : v[0];
    float b = (g & 1) ? v[3] : v[2];
    return (g & 2) ? b : a;
}

// 256 blocks x 1024 threads (16 waves = 4 waves/SIMD FORCED co-residency —
// R12/R13's 2-blocks/CU never co-scheduled; a single 16-wave block must).
// Block owns 4 batches. Wave w: role = w<8 (L0 of step it / L1 of step it-1),
// wg = w&3 (hidden group), pipe = (w>>2)&1 (batch pair {2P,2P+1}).
// Each SIMD hosts 2 L0 + 2 L1 waves with independent dep chains -> chains
// interleave within a phase, hiding the barrier/LDS/MFMA/trans latency that
// bounds R9. MFMA cols: 2 real batches duplicated x8 (b_own = 2*pipe+(bc&1));
// copy-group G=(bc>>1)&3 picks the acc reg -> each lane owns ONE
// (hidden,batch) cell in registers (writes gated to bc<8).
// R9's proven 1-barrier-per-phase pipeline; arithmetic identical per batch.
__global__ __launch_bounds__(1024, 1) void lstm_fused(
    const float* __restrict__ x,
    const float* __restrict__ Wih0, const float* __restrict__ Whh0,
    const float* __restrict__ bih0, const float* __restrict__ bhh0,
    const float* __restrict__ Wih1, const float* __restrict__ Whh1,
    const float* __restrict__ bih1, const float* __restrict__ bhh1,
    const float* __restrict__ fc1w, const float* __restrict__ fc1b,
    const float* __restrict__ fc2w, const float* __restrict__ fc2b,
    float* __restrict__ out)
{
    __shared__ __align__(16) f16 x_lds[2 * XHALF];    // ~33 KB
    __shared__ __align__(16) f16 h1buf[2 * HLAY];
    __shared__ __align__(16) f16 h2buf[2 * HLAY];
    __shared__ float zbuf[4][33];

    const int tid   = threadIdx.x;
    const int lane  = tid & 63;
    const int w     = tid >> 6;          // 0..15
    const int wg    = w & 3;             // hidden group within layer
    const int pipe  = (w >> 2) & 1;      // batch-pair pipeline
    const bool isL0 = (w < 8);
    const int bc    = lane & 15;         // MFMA col / A-row-in-tile
    const int lq    = lane >> 4;         // k-octet / D-row quad
    const int G     = (bc >> 1) & 3;     // acc reg this lane consumes
    const int b_own = 2 * pipe + (bc & 1);   // batch this lane's column carries
    const int bg0   = blockIdx.x * 4;

    // ---- one-time: pre-scaled A-fragments + bias C-init vectors ----
    const float wsc[4] = {NLOG2E, NLOG2E, N2LOG2E, NLOG2E};
    f16x8 A[4][4];
    f32x4 cb[4];
    #pragma unroll
    for (int g = 0; g < 4; ++g) {
        const int gr = g * 64 + 16 * wg + bc;
        #pragma unroll
        for (int s = 0; s < 4; ++s) {
            #pragma unroll
            for (int i = 0; i < 8; ++i) {
                int k = 32 * s + lq * 8 + i;
                float v = 0.0f;
                if (isL0) {
                    if (s < 3) v = (k < 32) ? Wih0[gr * 32 + k] : Whh0[gr * 64 + (k - 32)];
                } else {
                    v = (k < 64) ? Wih1[gr * 64 + k] : Whh1[gr * 64 + (k - 64)];
                }
                A[g][s][i] = (f16)(v * wsc[g]);
            }
        }
        #pragma unroll
        for (int r = 0; r < 4; ++r) {
            const int gd = g * 64 + 16 * wg + 4 * lq + r;
            float bb = isL0 ? (bih0[gd] + bhh0[gd]) : (bih1[gd] + bhh1[gd]);
            cb[g][r] = bb * wsc[g];
        }
    }

    // ---- zero h LDS ----
    for (int i = tid; i < 2 * HLAY; i += 1024) { h1buf[i] = (f16)0; h2buf[i] = (f16)0; }

    // ---- chunk refill: timesteps [64ch,64ch+64) of 4 batches, all 1024 thr ----
    const int rf_b   = tid >> 8;         // 0..3
    const int rf_rem = tid & 255;
#define REFILL(ch)                                                            \
    {                                                                         \
        f16* dst = x_lds + ((ch) & 1) * XHALF + rf_b * XBSTR;                 \
        const float4* src = (const float4*)(x +                               \
            ((long)(bg0 + rf_b) * TLEN + (ch) * XCH) * 32);                   \
        _Pragma("unroll")                                                     \
        for (int j = 0; j < 2; ++j) {                                         \
            float4 v = src[rf_rem + 256 * j];                                 \
            f16x4 hv;                                                         \
            hv[0]=(f16)v.x; hv[1]=(f16)v.y; hv[2]=(f16)v.z; hv[3]=(f16)v.w;   \
            *(f16x4*)(dst + (rf_rem + 256 * j) * 4) = hv;                     \
        }                                                                     \
    }

    REFILL(0)                       // chunk 0 -> parity 0
    __syncthreads();

    const int bch = b_own * HSTR + lq * 8;                 // broadcast h B-frag offset
    const int bxx = b_own * XBSTR + lq * 8;                // x B-frag offset
    const int hwr = b_own * HSTR + 16 * wg + 4 * lq + G;   // h write (bc<8 only)

    float cst = 0.0f;   // cell state of my (16wg+4lq+G, b_own)

#define CELL_UPDATE(HBUF, PW)                                                 \
    {                                                                         \
        float pi = sel4(a0, G);                                               \
        float pf = sel4(a1, G);                                               \
        float pg = sel4(a2, G);                                               \
        float po = sel4(a3, G);                                               \
        float iv = rcp_(1.0f + ex2(pi));                                      \
        float fv = rcp_(1.0f + ex2(pf));                                      \
        float gv = fmaf(2.0f, rcp_(1.0f + ex2(pg)), -1.0f);                   \
        float ov = rcp_(1.0f + ex2(po));                                      \
        cst = fmaf(fv, cst, iv * gv);                                         \
        float tc = fmaf(2.0f, rcp_(1.0f + ex2(cst * N2LOG2E)), -1.0f);        \
        if (bc < 8) HBUF[(PW) * HLAY + hwr] = (f16)(ov * tc);                 \
    }

// L0 at iteration it (parity p = it&1): reads x_lds chunk (it>>6), h1buf[p^1];
// writes h1buf[p].
#define L0_PHASE(p, itv)                                                      \
    {                                                                         \
        f16x8 b0 = *(const f16x8*)(x_lds + (((itv) >> 6) & 1) * XHALF +       \
                                   ((itv) & 63) * 32 + bxx);                  \
        f16x8 b1 = *(const f16x8*)(h1buf + ((p)^1) * HLAY + bch);             \
        f16x8 b2 = *(const f16x8*)(h1buf + ((p)^1) * HLAY + bch + 32);        \
        __builtin_amdgcn_s_setprio(1);                                        \
        f32x4 a0 = __builtin_amdgcn_mfma_f32_16x16x32_f16(A[0][0], b0, cb[0], 0,0,0); \
        f32x4 a1 = __builtin_amdgcn_mfma_f32_16x16x32_f16(A[1][0], b0, cb[1], 0,0,0); \
        f32x4 a2 = __builtin_amdgcn_mfma_f32_16x16x32_f16(A[2][0], b0, cb[2], 0,0,0); \
        f32x4 a3 = __builtin_amdgcn_mfma_f32_16x16x32_f16(A[3][0], b0, cb[3], 0,0,0); \
        a0 = __builtin_amdgcn_mfma_f32_16x16x32_f16(A[0][1], b1, a0, 0,0,0);  \
        a1 = __builtin_amdgcn_mfma_f32_16x16x32_f16(A[1][1], b1, a1, 0,0,0);  \
        a2 = __builtin_amdgcn_mfma_f32_16x16x32_f16(A[2][1], b1, a2, 0,0,0);  \
        a3 = __builtin_amdgcn_mfma_f32_16x16x32_f16(A[3][1], b1, a3, 0,0,0);  \
        a0 = __builtin_amdgcn_mfma_f32_16x16x32_f16(A[0][2], b2, a0, 0,0,0);  \
        a1 = __builtin_amdgcn_mfma_f32_16x16x32_f16(A[1][2], b2, a1, 0,0,0);  \
        a2 = __builtin_amdgcn_mfma_f32_16x16x32_f16(A[2][2], b2, a2, 0,0,0);  \
        a3 = __builtin_amdgcn_mfma_f32_16x16x32_f16(A[3][2], b2, a3, 0,0,0);  \
        __builtin_amdgcn_s_setprio(0);                                        \
        CELL_UPDATE(h1buf, p)                                                 \
    }

// L1 at iteration it (t = it-1, p = it&1): reads h1buf[p^1] (=h1[t]),
// h2buf[p] (=h2[t-1]); writes h2buf[p^1] (=h2[t]).
#define L1_PHASE(p)                                                           \
    {                                                                         \
        f16x8 b0 = *(const f16x8*)(h1buf + ((p)^1) * HLAY + bch);             \
        f16x8 b1 = *(const f16x8*)(h1buf + ((p)^1) * HLAY + bch + 32);        \
        f16x8 b2 = *(const f16x8*)(h2buf + (p) * HLAY + bch);                 \
        f16x8 b3 = *(const f16x8*)(h2buf + (p) * HLAY + bch + 32);            \
        __builtin_amdgcn_s_setprio(1);                                        \
        f32x4 a0 = __builtin_amdgcn_mfma_f32_16x16x32_f16(A[0][0], b0, cb[0], 0,0,0); \
        f32x4 a1 = __builtin_amdgcn_mfma_f32_16x16x32_f16(A[1][0], b0, cb[1], 0,0,0); \
        f32x4 a2 = __builtin_amdgcn_mfma_f32_16x16x32_f16(A[2][0], b0, cb[2], 0,0,0); \
        f32x4 a3 = __builtin_amdgcn_mfma_f32_16x16x32_f16(A[3][0], b0, cb[3], 0,0,0); \
        a0 = __builtin_amdgcn_mfma_f32_16x16x32_f16(A[0][1], b1, a0, 0,0,0);  \
        a1 = __builtin_amdgcn_mfma_f32_16x16x32_f16(A[1][1], b1, a1, 0,0,0);  \
        a2 = __builtin_amdgcn_mfma_f32_16x16x32_f16(A[2][1], b1, a2, 0,0,0);  \
        a3 = __builtin_amdgcn_mfma_f32_16x16x32_f16(A[3][1], b1, a3, 0,0,0);  \
        a0 = __builtin_amdgcn_mfma_f32_16x16x32_f16(A[0][2], b2, a0, 0,0,0);  \
        a1 = __builtin_amdgcn_mfma_f32_16x16x32_f16(A[1][2], b2, a1, 0,0,0);  \
        a2 = __builtin_amdgcn_mfma_f32_16x16x32_f16(A[2][2], b2, a2, 0,0,0);  \
        a3 = __builtin_amdgcn_mfma_f32_16x16x32_f16(A[3][2], b2, a3, 0,0,0);  \
        a0 = __builtin_amdgcn_mfma_f32_16x16x32_f16(A[0][3], b3, a0, 0,0,0);  \
        a1 = __builtin_amdgcn_mfma_f32_16x16x32_f16(A[1][3], b3, a1, 0,0,0);  \
        a2 = __builtin_amdgcn_mfma_f32_16x16x32_f16(A[2][3], b3, a2, 0,0,0);  \
        a3 = __builtin_amdgcn_mfma_f32_16x16x32_f16(A[3][3], b3, a3, 0,0,0);  \
        __builtin_amdgcn_s_setprio(0);                                        \
        CELL_UPDATE(h2buf, (p)^1)                                             \
    }

    // ---- pipeline: it = 0 .. 512 ----
    if (isL0) L0_PHASE(0, 0)            // it = 0
    REFILL(1)                           // chunk 1 -> parity 1 (reads start at it=64)
    __syncthreads();

    #pragma unroll 1
    for (int k = 0; k < 255; ++k) {     // it = 2k+1, 2k+2  (1..510)
        if (isL0) L0_PHASE(1, 2 * k + 1) else L1_PHASE(1)
        __syncthreads();
        const int it2 = 2 * k + 2;
        if (isL0) L0_PHASE(0, it2) else L1_PHASE(0)
        if ((it2 & (XCH - 1)) == 0 && it2 <= TLEN - 2 * XCH)
            REFILL((it2 >> 6) + 1)      // chunk c+1 at it=64c (c=1..6)
        __syncthreads();
    }

    if (isL0) L0_PHASE(1, 511) else L1_PHASE(1)   // it = 511
    __syncthreads();
    if (!isL0) L1_PHASE(0)                        // it = 512 (L1 finishes h2[511])
    __syncthreads();

#undef L0_PHASE
#undef L1_PHASE
#undef CELL_UPDATE
#undef REFILL

    // ---- FC head: h2[511] is in parity 1 ----
    const f16* h2f = h2buf + HLAY;
    if (tid < 128) {
        int b = tid >> 5, m = tid & 31;
        float z = fc1b[m];
        #pragma unroll
        for (int j = 0; j < 64; ++j)
            z = fmaf(fc1w[m * 64 + j], (float)h2f[b * HSTR + j], z);
        zbuf[b][m] = fmaxf(z, 0.0f);
    }
    __syncthreads();
    if (tid < 8) {
        int b = tid >> 1, o = tid & 1;
        float s = fc2b[o];
        #pragma unroll
        for (int m = 0; m < 32; ++m)
            s = fmaf(fc2w[o * 32 + m], zbuf[b][m], s);
        out[(long)(bg0 + b) * 2 + o] = s;
    }
}

extern "C" void kernel_launch(void* const* d_in, const int* in_sizes, int n_in,
                              void* d_out, int out_size, void* d_ws, size_t ws_size,
                              hipStream_t stream) {
    const float* x    = (const float*)d_in[0];
    const float* Wih0 = (const float*)d_in[1];
    const float* Whh0 = (const float*)d_in[2];
    const float* bih0 = (const float*)d_in[3];
    const float* bhh0 = (const float*)d_in[4];
    const float* Wih1 = (const float*)d_in[5];
    const float* Whh1 = (const float*)d_in[6];
    const float* bih1 = (const float*)d_in[7];
    const float* bhh1 = (const float*)d_in[8];
    const float* fc1w = (const float*)d_in[9];
    const float* fc1b = (const float*)d_in[10];
    const float* fc2w = (const float*)d_in[11];
    const float* fc2b = (const float*)d_in[12];
    float* out = (float*)d_out;

    lstm_fused<<<dim3(NB / 4), dim3(1024), 0, stream>>>(
        x, Wih0, Whh0, bih0, bhh0, Wih1, Whh1, bih1, bhh1,
        fc1w, fc1b, fc2w, fc2b, out);
}

// Round 15
// 386.911 us; speedup vs baseline: 1.1713x; 1.0665x over previous
//
#include <hip/hip_runtime.h>
#include <math.h>

#define TLEN 512
#define NB   1024
#define BPB  2                  // batches per block
#define HSTR 80                 // h buf row stride (f16): 40 dwords -> <=2-way
#define HLAY (BPB * HSTR)       // one parity of h buffer
#define XCH  64                 // timesteps per x chunk
#define XBSTR (XCH * 32 + 16)   // per-batch chunk stride (f16): 1032 dw = 8 mod 32
#define XHALF (BPB * XBSTR)     // one chunk buffer

#define NLOG2E  (-1.44269504f)  // -log2(e): sigmoid gates
#define N2LOG2E (-2.88539008f)  // -2log2(e): tanh gate / tanh(c)

typedef _Float16 f16;
typedef f16   f16x4 __attribute__((ext_vector_type(4)));
typedef f16   f16x8 __attribute__((ext_vector_type(8)));
typedef float f32x4 __attribute__((ext_vector_type(4)));

__device__ __forceinline__ float ex2(float x) {
#if __has_builtin(__builtin_amdgcn_exp2f)
    return __builtin_amdgcn_exp2f(x);
#else
    return exp2f(x);
#endif
}
__device__ __forceinline__ float rcp_(float x) { return __builtin_amdgcn_rcpf(x); }
__device__ __forceinline__ float sel4(f32x4 v, int g) {
    float a = (g & 1) ? v[1] : v[0];
    float b = (g & 1) ? v[3] : v[2];
    return (g & 2) ? b : a;
}

// 512 blocks x 256 threads (4 waves). Block owns 2 batches; wave wg handles
// hidden group 16wg..16wg+15 for BOTH layers (A0+A1 in regs, ~196 VGPR, under
// the 256 tier for 2 waves/SIMD). 2 blocks/CU = 8 waves = exactly 2 waves/SIMD
// -> each SIMD hosts one wave from each of TWO INDEPENDENT BARRIER DOMAINS:
// their phases stagger naturally, so one block's MFMA/act/LDS-latency windows
// absorb the other's stalls (R9's lockstep waves collided on the same pipes).
// Per step: L0 sub-phase -> barrier -> L1 sub-phase -> barrier. No layer skew.
// MFMA cols: 2 real batches duplicated x8 (b_own=bc&1); copy-group G=(bc>>1)&3
// picks the acc reg -> each lane owns ONE (hidden,batch) cell per layer in
// registers (writes gated to bc<8). Arithmetic per batch identical to R9.
__global__ __launch_bounds__(256, 2) void lstm_fused(
    const float* __restrict__ x,
    const float* __restrict__ Wih0, const float* __restrict__ Whh0,
    const float* __restrict__ bih0, const float* __restrict__ bhh0,
    const float* __restrict__ Wih1, const float* __restrict__ Whh1,
    const float* __restrict__ bih1, const float* __restrict__ bhh1,
    const float* __restrict__ fc1w, const float* __restrict__ fc1b,
    const float* __restrict__ fc2w, const float* __restrict__ fc2b,
    float* __restrict__ out)
{
    __shared__ __align__(16) f16 x_lds[2 * XHALF];    // ~16.5 KB
    __shared__ __align__(16) f16 h1buf[2 * HLAY];
    __shared__ __align__(16) f16 h2buf[2 * HLAY];
    __shared__ float zbuf[BPB][33];

    const int tid   = threadIdx.x;
    const int lane  = tid & 63;
    const int wg    = tid >> 6;          // wave = hidden group 0..3
    const int bc    = lane & 15;         // MFMA col / A-row-in-tile
    const int lq    = lane >> 4;         // k-octet / D-row quad
    const int G     = (bc >> 1) & 3;     // acc reg this lane consumes
    const int b_own = bc & 1;            // batch this lane's column carries
    const int bg0   = blockIdx.x * BPB;

    // ---- one-time: pre-scaled A-fragments + bias C-init for BOTH layers ----
    const float wsc[4] = {NLOG2E, NLOG2E, N2LOG2E, NLOG2E};
    f16x8 A0[4][3], A1[4][4];
    f32x4 cb0[4], cb1[4];
    #pragma unroll
    for (int g = 0; g < 4; ++g) {
        const int gr = g * 64 + 16 * wg + bc;
        #pragma unroll
        for (int s = 0; s < 3; ++s)
            #pragma unroll
            for (int i = 0; i < 8; ++i) {
                int k = 32 * s + lq * 8 + i;      // K=96: [x(32)|h1(64)]
                float v = (k < 32) ? Wih0[gr * 32 + k] : Whh0[gr * 64 + (k - 32)];
                A0[g][s][i] = (f16)(v * wsc[g]);
            }
        #pragma unroll
        for (int s = 0; s < 4; ++s)
            #pragma unroll
            for (int i = 0; i < 8; ++i) {
                int k = 32 * s + lq * 8 + i;      // K=128: [h1(64)|h2(64)]
                float v = (k < 64) ? Wih1[gr * 64 + k] : Whh1[gr * 64 + (k - 64)];
                A1[g][s][i] = (f16)(v * wsc[g]);
            }
        #pragma unroll
        for (int r = 0; r < 4; ++r) {
            const int gd = g * 64 + 16 * wg + 4 * lq + r;
            cb0[g][r] = (bih0[gd] + bhh0[gd]) * wsc[g];
            cb1[g][r] = (bih1[gd] + bhh1[gd]) * wsc[g];
        }
    }

    // ---- zero h LDS ----
    for (int i = tid; i < 2 * HLAY; i += 256) { h1buf[i] = (f16)0; h2buf[i] = (f16)0; }

    // ---- chunk refill: timesteps [64ch,64ch+64) of 2 batches, 256 threads ----
    const int rf_b   = tid >> 7;         // 0..1
    const int rf_rem = tid & 127;
#define REFILL(ch)                                                            \
    {                                                                         \
        f16* dst = x_lds + ((ch) & 1) * XHALF + rf_b * XBSTR;                 \
        const float4* src = (const float4*)(x +                               \
            ((long)(bg0 + rf_b) * TLEN + (ch) * XCH) * 32);                   \
        _Pragma("unroll")                                                     \
        for (int j = 0; j < 4; ++j) {                                         \
            float4 v = src[rf_rem + 128 * j];                                 \
            f16x4 hv;                                                         \
            hv[0]=(f16)v.x; hv[1]=(f16)v.y; hv[2]=(f16)v.z; hv[3]=(f16)v.w;   \
            *(f16x4*)(dst + (rf_rem + 128 * j) * 4) = hv;                     \
        }                                                                     \
    }

    REFILL(0)                       // chunk 0 -> parity 0
    __syncthreads();

    const int bch = b_own * HSTR + lq * 8;                 // broadcast h B-frag offset
    const int bxx = b_own * XBSTR + lq * 8;                // x B-frag offset
    const int hwr = b_own * HSTR + 16 * wg + 4 * lq + G;   // h write (bc<8 only)

    float cst0 = 0.0f, cst1 = 0.0f;

#define ACT_STORE(CST, HBUF, PW)                                              \
    {                                                                         \
        float pi = sel4(a0, G);                                               \
        float pf = sel4(a1, G);                                               \
        float pg = sel4(a2, G);                                               \
        float po = sel4(a3, G);                                               \
        float iv = rcp_(1.0f + ex2(pi));                                      \
        float fv = rcp_(1.0f + ex2(pf));                                      \
        float gv = fmaf(2.0f, rcp_(1.0f + ex2(pg)), -1.0f);                   \
        float ov = rcp_(1.0f + ex2(po));                                      \
        CST = fmaf(fv, CST, iv * gv);                                         \
        float tc = fmaf(2.0f, rcp_(1.0f + ex2(CST * N2LOG2E)), -1.0f);        \
        if (bc < 8) HBUF[(PW) * HLAY + hwr] = (f16)(ov * tc);                 \
    }

// L0 sub-phase at step t (parity p): reads x[t], h1buf[p^1]; writes h1buf[p].
#define L0_PART(p, tv)                                                        \
    {                                                                         \
        f16x8 b0 = *(const f16x8*)(x_lds + (((tv) >> 6) & 1) * XHALF +        \
                                   ((tv) & 63) * 32 + bxx);                   \
        f16x8 b1 = *(const f16x8*)(h1buf + ((p)^1) * HLAY + bch);             \
        f16x8 b2 = *(const f16x8*)(h1buf + ((p)^1) * HLAY + bch + 32);        \
        __builtin_amdgcn_s_setprio(1);                                        \
        f32x4 a0 = __builtin_amdgcn_mfma_f32_16x16x32_f16(A0[0][0], b0, cb0[0], 0,0,0); \
        f32x4 a1 = __builtin_amdgcn_mfma_f32_16x16x32_f16(A0[1][0], b0, cb0[1], 0,0,0); \
        f32x4 a2 = __builtin_amdgcn_mfma_f32_16x16x32_f16(A0[2][0], b0, cb0[2], 0,0,0); \
        f32x4 a3 = __builtin_amdgcn_mfma_f32_16x16x32_f16(A0[3][0], b0, cb0[3], 0,0,0); \
        a0 = __builtin_amdgcn_mfma_f32_16x16x32_f16(A0[0][1], b1, a0, 0,0,0); \
        a1 = __builtin_amdgcn_mfma_f32_16x16x32_f16(A0[1][1], b1, a1, 0,0,0); \
        a2 = __builtin_amdgcn_mfma_f32_16x16x32_f16(A0[2][1], b1, a2, 0,0,0); \
        a3 = __builtin_amdgcn_mfma_f32_16x16x32_f16(A0[3][1], b1, a3, 0,0,0); \
        a0 = __builtin_amdgcn_mfma_f32_16x16x32_f16(A0[0][2], b2, a0, 0,0,0); \
        a1 = __builtin_amdgcn_mfma_f32_16x16x32_f16(A0[1][2], b2, a1, 0,0,0); \
        a2 = __builtin_amdgcn_mfma_f32_16x16x32_f16(A0[2][2], b2, a2, 0,0,0); \
        a3 = __builtin_amdgcn_mfma_f32_16x16x32_f16(A0[3][2], b2, a3, 0,0,0); \
        __builtin_amdgcn_s_setprio(0);                                        \
        if (((tv) & 63) == 0 && (tv) <= TLEN - 2 * XCH)                       \
            REFILL(((tv) >> 6) + 1)                                           \
        ACT_STORE(cst0, h1buf, p)                                             \
    }

// L1 sub-phase at step t (parity p): reads h1buf[p] (=h1[t], crossed the mid
// barrier), h2buf[p^1] (=h2[t-1]); writes h2buf[p].
#define L1_PART(p)                                                            \
    {                                                                         \
        f16x8 b0 = *(const f16x8*)(h1buf + (p) * HLAY + bch);                 \
        f16x8 b1 = *(const f16x8*)(h1buf + (p) * HLAY + bch + 32);            \
        f16x8 b2 = *(const f16x8*)(h2buf + ((p)^1) * HLAY + bch);             \
        f16x8 b3 = *(const f16x8*)(h2buf + ((p)^1) * HLAY + bch + 32);        \
        __builtin_amdgcn_s_setprio(1);                                        \
        f32x4 a0 = __builtin_amdgcn_mfma_f32_16x16x32_f16(A1[0][0], b0, cb1[0], 0,0,0); \
        f32x4 a1 = __builtin_amdgcn_mfma_f32_16x16x32_f16(A1[1][0], b0, cb1[1], 0,0,0); \
        f32x4 a2 = __builtin_amdgcn_mfma_f32_16x16x32_f16(A1[2][0], b0, cb1[2], 0,0,0); \
        f32x4 a3 = __builtin_amdgcn_mfma_f32_16x16x32_f16(A1[3][0], b0, cb1[3], 0,0,0); \
        a0 = __builtin_amdgcn_mfma_f32_16x16x32_f16(A1[0][1], b1, a0, 0,0,0); \
        a1 = __builtin_amdgcn_mfma_f32_16x16x32_f16(A1[1][1], b1, a1, 0,0,0); \
        a2 = __builtin_amdgcn_mfma_f32_16x16x32_f16(A1[2][1], b1, a2, 0,0,0); \
        a3 = __builtin_amdgcn_mfma_f32_16x16x32_f16(A1[3][1], b1, a3, 0,0,0); \
        a0 = __builtin_amdgcn_mfma_f32_16x16x32_f16(A1[0][2], b2, a0, 0,0,0); \
        a1 = __builtin_amdgcn_mfma_f32_16x16x32_f16(A1[1][2], b2, a1, 0,0,0); \
        a2 = __builtin_amdgcn_mfma_f32_16x16x32_f16(A1[2][2], b2, a2, 0,0,0); \
        a3 = __builtin_amdgcn_mfma_f32_16x16x32_f16(A1[3][2], b2, a3, 0,0,0); \
        a0 = __builtin_amdgcn_mfma_f32_16x16x32_f16(A1[0][3], b3, a0, 0,0,0); \
        a1 = __builtin_amdgcn_mfma_f32_16x16x32_f16(A1[1][3], b3, a1, 0,0,0); \
        a2 = __builtin_amdgcn_mfma_f32_16x16x32_f16(A1[2][3], b3, a2, 0,0,0); \
        a3 = __builtin_amdgcn_mfma_f32_16x16x32_f16(A1[3][3], b3, a3, 0,0,0); \
        __builtin_amdgcn_s_setprio(0);                                        \
        ACT_STORE(cst1, h2buf, p)                                             \
    }

    // ---- main loop: both layers advance together, 2 barriers/step ----
    #pragma unroll 1
    for (int k = 0; k < 256; ++k) {
        const int te = 2 * k;
        L0_PART(0, te)
        __syncthreads();        // h1[te] visible
        L1_PART(0)
        __syncthreads();        // h2[te] visible; h1/h2 parity-0 reads done
        L0_PART(1, te + 1)
        __syncthreads();
        L1_PART(1)
        __syncthreads();
    }

#undef L0_PART
#undef L1_PART
#undef ACT_STORE
#undef REFILL

    // ---- FC head: h2[511] is in parity 1 ----
    const f16* h2f = h2buf + HLAY;
    if (tid < 64) {
        int b = tid >> 5, m = tid & 31;
        float z = fc1b[m];
        #pragma unroll
        for (int j = 0; j < 64; ++j)
            z = fmaf(fc1w[m * 64 + j], (float)h2f[b * HSTR + j], z);
        zbuf[b][m] = fmaxf(z, 0.0f);
    }
    __syncthreads();
    if (tid < 4) {
        int b = tid >> 1, o = tid & 1;
        float s = fc2b[o];
        #pragma unroll
        for (int m = 0; m < 32; ++m)
            s = fmaf(fc2w[o * 32 + m], zbuf[b][m], s);
        out[(long)(bg0 + b) * 2 + o] = s;
    }
}

extern "C" void kernel_launch(void* const* d_in, const int* in_sizes, int n_in,
                              void* d_out, int out_size, void* d_ws, size_t ws_size,
                              hipStream_t stream) {
    const float* x    = (const float*)d_in[0];
    const float* Wih0 = (const float*)d_in[1];
    const float* Whh0 = (const float*)d_in[2];
    const float* bih0 = (const float*)d_in[3];
    const float* bhh0 = (const float*)d_in[4];
    const float* Wih1 = (const float*)d_in[5];
    const float* Whh1 = (const float*)d_in[6];
    const float* bih1 = (const float*)d_in[7];
    const float* bhh1 = (const float*)d_in[8];
    const float* fc1w = (const float*)d_in[9];
    const float* fc1b = (const float*)d_in[10];
    const float* fc2w = (const float*)d_in[11];
    const float* fc2b = (const float*)d_in[12];
    float* out = (float*)d_out;

    lstm_fused<<<dim3(NB / BPB), dim3(256), 0, stream>>>(
        x, Wih0, Whh0, bih0, bhh0, Wih1, Whh1, bih1, bhh1,
        fc1w, fc1b, fc2w, fc2b, out);
}

// Round 16
// 227.494 us; speedup vs baseline: 1.9921x; 1.7008x over previous
//
#include <hip/hip_runtime.h>
#include <math.h>

#define TLEN 512
#define NB   1024
#define HSTR 80                 // h buf row stride (f16): 40 dwords -> <=2-way
#define HLAY (4 * HSTR)
#define XCH  64                 // timesteps per x chunk
#define XBSTR (XCH * 32 + 16)   // per-batch chunk stride (f16)
#define XHALF (4 * XBSTR)       // one chunk buffer (4 batches)

#define NLOG2E  (-1.44269504f)  // -log2(e): sigmoid gates
#define N2LOG2E (-2.88539008f)  // -2log2(e): tanh gate / tanh(c)

typedef _Float16 f16;
typedef f16   f16x4 __attribute__((ext_vector_type(4)));
typedef f16   f16x8 __attribute__((ext_vector_type(8)));
typedef float f32x4 __attribute__((ext_vector_type(4)));

__device__ __forceinline__ float ex2(float x) {
#if __has_builtin(__builtin_amdgcn_exp2f)
    return __builtin_amdgcn_exp2f(x);
#else
    return exp2f(x);
#endif
}
__device__ __forceinline__ float rcp_(float x) { return __builtin_amdgcn_rcpf(x); }
__device__ __forceinline__ float sel4(f32x4 v, int g) {
    float a = (g & 1) ? v[1] : v[0];
    float b = (g & 1) ? v[3] : v[2];
    return (g & 2) ? b : a;
}

// FINAL (= round 9, best measured: 227 µs, absmax 2.44e-4).
// 256 blocks x 512 threads (8 waves, 2/SIMD: one L0 + one L1 wave).
// Waves 0-3: layer 0 of step it; waves 4-7: layer 1 of step it-1 (pipelined),
// 1 barrier per phase. Broadcast B-reads (lane bc reads batch bc&3, MFMA cols
// 4-15 duplicate cols 0-3); copy-group G=bc>>2 consumes acc reg r=G -> each
// lane owns ONE (hidden,batch) cell entirely in registers. Weights pre-scaled
// by -log2e (-2log2e for tanh gate) so activations are rcp(1+exp2(v)); biases
// ride in the MFMA C operand. x staged through LDS in 64-step double-buffered
// chunks (zero global ops in steady state).
// Structural floor notes (R10-R15 falsifications): latency-chain-bound;
// 2-blocks/CU and >2 waves/SIMD variants all fail on the ~92-VGPR/wave
// register-resident-weight requirement (spill or no co-placement).
__global__ __launch_bounds__(512, 1) void lstm_fused(
    const float* __restrict__ x,
    const float* __restrict__ Wih0, const float* __restrict__ Whh0,
    const float* __restrict__ bih0, const float* __restrict__ bhh0,
    const float* __restrict__ Wih1, const float* __restrict__ Whh1,
    const float* __restrict__ bih1, const float* __restrict__ bhh1,
    const float* __restrict__ fc1w, const float* __restrict__ fc1b,
    const float* __restrict__ fc2w, const float* __restrict__ fc2b,
    float* __restrict__ out)
{
    __shared__ __align__(16) f16 x_lds[2 * XHALF];    // ~33 KB
    __shared__ __align__(16) f16 h1buf[2 * HLAY];
    __shared__ __align__(16) f16 h2buf[2 * HLAY];
    __shared__ float zbuf[4][33];

    const int tid   = threadIdx.x;
    const int lane  = tid & 63;
    const int w     = tid >> 6;          // 0..7
    const int wg    = w & 3;             // hidden group within layer
    const bool isL0 = (w < 4);
    const int bc    = lane & 15;         // MFMA col / A-row-in-tile
    const int lq    = lane >> 4;         // k-octet / D-row quad
    const int G     = bc >> 2;           // copy-group -> acc reg this lane consumes
    const int b_own = bc & 3;            // batch this lane's column carries
    const int bg0   = blockIdx.x * 4;

    // ---- one-time: pre-scaled A-fragments + bias C-init vectors ----
    const float wsc[4] = {NLOG2E, NLOG2E, N2LOG2E, NLOG2E};
    f16x8 A[4][4];
    f32x4 cb[4];
    #pragma unroll
    for (int g = 0; g < 4; ++g) {
        const int gr = g * 64 + 16 * wg + bc;
        #pragma unroll
        for (int s = 0; s < 4; ++s) {
            #pragma unroll
            for (int i = 0; i < 8; ++i) {
                int k = 32 * s + lq * 8 + i;
                float v = 0.0f;
                if (isL0) {
                    if (s < 3) v = (k < 32) ? Wih0[gr * 32 + k] : Whh0[gr * 64 + (k - 32)];
                } else {
                    v = (k < 64) ? Wih1[gr * 64 + k] : Whh1[gr * 64 + (k - 64)];
                }
                A[g][s][i] = (f16)(v * wsc[g]);
            }
        }
        #pragma unroll
        for (int r = 0; r < 4; ++r) {
            const int gd = g * 64 + 16 * wg + 4 * lq + r;   // D-row gate index
            float bb = isL0 ? (bih0[gd] + bhh0[gd]) : (bih1[gd] + bhh1[gd]);
            cb[g][r] = bb * wsc[g];
        }
    }

    // ---- zero h LDS ----
    for (int i = tid; i < 2 * HLAY; i += 512) { h1buf[i] = (f16)0; h2buf[i] = (f16)0; }

    // chunk refill: timesteps [64ch, 64ch+64) of 4 batches -> x_lds parity ch&1.
    const int rf_b   = tid >> 7;         // 0..3
    const int rf_rem = tid & 127;
#define REFILL(ch)                                                            \
    {                                                                         \
        f16* dst = x_lds + ((ch) & 1) * XHALF + rf_b * XBSTR;                 \
        const float4* src = (const float4*)(x +                               \
            ((long)(bg0 + rf_b) * TLEN + (ch) * XCH) * 32);                   \
        float4 v0 = src[rf_rem];                                              \
        float4 v1 = src[rf_rem + 128];                                        \
        float4 v2 = src[rf_rem + 256];                                        \
        float4 v3 = src[rf_rem + 384];                                        \
        f16x4 h;                                                              \
        h[0]=(f16)v0.x; h[1]=(f16)v0.y; h[2]=(f16)v0.z; h[3]=(f16)v0.w;       \
        *(f16x4*)(dst + (rf_rem)       * 4) = h;                              \
        h[0]=(f16)v1.x; h[1]=(f16)v1.y; h[2]=(f16)v1.z; h[3]=(f16)v1.w;       \
        *(f16x4*)(dst + (rf_rem + 128) * 4) = h;                              \
        h[0]=(f16)v2.x; h[1]=(f16)v2.y; h[2]=(f16)v2.z; h[3]=(f16)v2.w;       \
        *(f16x4*)(dst + (rf_rem + 256) * 4) = h;                              \
        h[0]=(f16)v3.x; h[1]=(f16)v3.y; h[2]=(f16)v3.z; h[3]=(f16)v3.w;       \
        *(f16x4*)(dst + (rf_rem + 384) * 4) = h;                              \
    }

    REFILL(0)                       // chunk 0 -> parity 0
    __syncthreads();

    const int bch = b_own * HSTR + lq * 8;                 // broadcast h B-frag offset
    const int bxx = b_own * XBSTR + lq * 8;                // x B-frag offset
    const int hwr = b_own * HSTR + 16 * wg + 4 * lq + G;   // h write

    float cst = 0.0f;   // cell state of my (16wg+4lq+G, b_own)

#define CELL_UPDATE(HBUF, PW)                                                 \
    {                                                                         \
        float pi = sel4(a0, G);                                               \
        float pf = sel4(a1, G);                                               \
        float pg = sel4(a2, G);                                               \
        float po = sel4(a3, G);                                               \
        float iv = rcp_(1.0f + ex2(pi));                                      \
        float fv = rcp_(1.0f + ex2(pf));                                      \
        float gv = fmaf(2.0f, rcp_(1.0f + ex2(pg)), -1.0f);                   \
        float ov = rcp_(1.0f + ex2(po));                                      \
        cst = fmaf(fv, cst, iv * gv);                                         \
        float tc = fmaf(2.0f, rcp_(1.0f + ex2(cst * N2LOG2E)), -1.0f);        \
        HBUF[(PW) * HLAY + hwr] = (f16)(ov * tc);                             \
    }

// L0 at iteration it (parity p = it&1): reads x_lds chunk (it>>6), h1buf[p^1];
// writes h1buf[p].
#define L0_PHASE(p, itv)                                                      \
    {                                                                         \
        f16x8 b0 = *(const f16x8*)(x_lds + (((itv) >> 6) & 1) * XHALF +       \
                                   ((itv) & (XCH - 1)) * 32 + bxx);           \
        f16x8 b1 = *(const f16x8*)(h1buf + ((p)^1) * HLAY + bch);             \
        f16x8 b2 = *(const f16x8*)(h1buf + ((p)^1) * HLAY + bch + 32);        \
        __builtin_amdgcn_s_setprio(1);                                        \
        f32x4 a0 = __builtin_amdgcn_mfma_f32_16x16x32_f16(A[0][0], b0, cb[0], 0,0,0); \
        f32x4 a1 = __builtin_amdgcn_mfma_f32_16x16x32_f16(A[1][0], b0, cb[1], 0,0,0); \
        f32x4 a2 = __builtin_amdgcn_mfma_f32_16x16x32_f16(A[2][0], b0, cb[2], 0,0,0); \
        f32x4 a3 = __builtin_amdgcn_mfma_f32_16x16x32_f16(A[3][0], b0, cb[3], 0,0,0); \
        a0 = __builtin_amdgcn_mfma_f32_16x16x32_f16(A[0][1], b1, a0, 0,0,0);  \
        a1 = __builtin_amdgcn_mfma_f32_16x16x32_f16(A[1][1], b1, a1, 0,0,0);  \
        a2 = __builtin_amdgcn_mfma_f32_16x16x32_f16(A[2][1], b1, a2, 0,0,0);  \
        a3 = __builtin_amdgcn_mfma_f32_16x16x32_f16(A[3][1], b1, a3, 0,0,0);  \
        a0 = __builtin_amdgcn_mfma_f32_16x16x32_f16(A[0][2], b2, a0, 0,0,0);  \
        a1 = __builtin_amdgcn_mfma_f32_16x16x32_f16(A[1][2], b2, a1, 0,0,0);  \
        a2 = __builtin_amdgcn_mfma_f32_16x16x32_f16(A[2][2], b2, a2, 0,0,0);  \
        a3 = __builtin_amdgcn_mfma_f32_16x16x32_f16(A[3][2], b2, a3, 0,0,0);  \
        __builtin_amdgcn_s_setprio(0);                                        \
        CELL_UPDATE(h1buf, p)                                                 \
    }

// L1 at iteration it (t = it-1, p = it&1): reads h1buf[p^1] (=h1[t]),
// h2buf[p] (=h2[t-1]); writes h2buf[p^1] (=h2[t]).
#define L1_PHASE(p)                                                           \
    {                                                                         \
        f16x8 b0 = *(const f16x8*)(h1buf + ((p)^1) * HLAY + bch);             \
        f16x8 b1 = *(const f16x8*)(h1buf + ((p)^1) * HLAY + bch + 32);        \
        f16x8 b2 = *(const f16x8*)(h2buf + (p) * HLAY + bch);                 \
        f16x8 b3 = *(const f16x8*)(h2buf + (p) * HLAY + bch + 32);            \
        __builtin_amdgcn_s_setprio(1);                                        \
        f32x4 a0 = __builtin_amdgcn_mfma_f32_16x16x32_f16(A[0][0], b0, cb[0], 0,0,0); \
        f32x4 a1 = __builtin_amdgcn_mfma_f32_16x16x32_f16(A[1][0], b0, cb[1], 0,0,0); \
        f32x4 a2 = __builtin_amdgcn_mfma_f32_16x16x32_f16(A[2][0], b0, cb[2], 0,0,0); \
        f32x4 a3 = __builtin_amdgcn_mfma_f32_16x16x32_f16(A[3][0], b0, cb[3], 0,0,0); \
        a0 = __builtin_amdgcn_mfma_f32_16x16x32_f16(A[0][1], b1, a0, 0,0,0);  \
        a1 = __builtin_amdgcn_mfma_f32_16x16x32_f16(A[1][1], b1, a1, 0,0,0);  \
        a2 = __builtin_amdgcn_mfma_f32_16x16x32_f16(A[2][1], b1, a2, 0,0,0);  \
        a3 = __builtin_amdgcn_mfma_f32_16x16x32_f16(A[3][1], b1, a3, 0,0,0);  \
        a0 = __builtin_amdgcn_mfma_f32_16x16x32_f16(A[0][2], b2, a0, 0,0,0);  \
        a1 = __builtin_amdgcn_mfma_f32_16x16x32_f16(A[1][2], b2, a1, 0,0,0);  \
        a2 = __builtin_amdgcn_mfma_f32_16x16x32_f16(A[2][2], b2, a2, 0,0,0);  \
        a3 = __builtin_amdgcn_mfma_f32_16x16x32_f16(A[3][2], b2, a3, 0,0,0);  \
        a0 = __builtin_amdgcn_mfma_f32_16x16x32_f16(A[0][3], b3, a0, 0,0,0);  \
        a1 = __builtin_amdgcn_mfma_f32_16x16x32_f16(A[1][3], b3, a1, 0,0,0);  \
        a2 = __builtin_amdgcn_mfma_f32_16x16x32_f16(A[2][3], b3, a2, 0,0,0);  \
        a3 = __builtin_amdgcn_mfma_f32_16x16x32_f16(A[3][3], b3, a3, 0,0,0);  \
        __builtin_amdgcn_s_setprio(0);                                        \
        CELL_UPDATE(h2buf, (p)^1)                                             \
    }

    // ---- pipeline: it = 0 .. 512 ----
    if (isL0) L0_PHASE(0, 0)            // it = 0
    REFILL(1)                           // chunk 1 -> parity 1 (reads start at it=64)
    __syncthreads();

    #pragma unroll 1
    for (int k = 0; k < 255; ++k) {     // it = 2k+1, 2k+2  (1..510)
        if (isL0) L0_PHASE(1, 2 * k + 1) else L1_PHASE(1)
        __syncthreads();
        const int it2 = 2 * k + 2;
        if (isL0) L0_PHASE(0, it2) else L1_PHASE(0)
        if ((it2 & (XCH - 1)) == 0 && it2 <= TLEN - 2 * XCH)
            REFILL((it2 >> 6) + 1)      // chunk c+1 at it=64c (c=1..6)
        __syncthreads();
    }

    if (isL0) L0_PHASE(1, 511) else L1_PHASE(1)   // it = 511
    __syncthreads();
    if (!isL0) L1_PHASE(0)                        // it = 512 (L1 finishes h2[511])
    __syncthreads();

#undef L0_PHASE
#undef L1_PHASE
#undef CELL_UPDATE
#undef REFILL

    // ---- FC head: h2[511] is in parity 1 ----
    const f16* h2f = h2buf + HLAY;
    if (tid < 128) {
        int b = tid >> 5, m = tid & 31;
        float z = fc1b[m];
        #pragma unroll
        for (int j = 0; j < 64; ++j)
            z = fmaf(fc1w[m * 64 + j], (float)h2f[b * HSTR + j], z);
        zbuf[b][m] = fmaxf(z, 0.0f);
    }
    __syncthreads();
    if (tid < 8) {
        int b = tid >> 1, o = tid & 1;
        float s = fc2b[o];
        #pragma unroll
        for (int m = 0; m < 32; ++m)
            s = fmaf(fc2w[o * 32 + m], zbuf[b][m], s);
        out[(long)(bg0 + b) * 2 + o] = s;
    }
}

extern "C" void kernel_launch(void* const* d_in, const int* in_sizes, int n_in,
                              void* d_out, int out_size, void* d_ws, size_t ws_size,
                              hipStream_t stream) {
    const float* x    = (const float*)d_in[0];
    const float* Wih0 = (const float*)d_in[1];
    const float* Whh0 = (const float*)d_in[2];
    const float* bih0 = (const float*)d_in[3];
    const float* bhh0 = (const float*)d_in[4];
    const float* Wih1 = (const float*)d_in[5];
    const float* Whh1 = (const float*)d_in[6];
    const float* bih1 = (const float*)d_in[7];
    const float* bhh1 = (const float*)d_in[8];
    const float* fc1w = (const float*)d_in[9];
    const float* fc1b = (const float*)d_in[10];
    const float* fc2w = (const float*)d_in[11];
    const float* fc2b = (const float*)d_in[12];
    float* out = (float*)d_out;

    lstm_fused<<<dim3(NB / 4), dim3(512), 0, stream>>>(
        x, Wih0, Whh0, bih0, bhh0, Wih1, Whh1, bih1, bhh1,
        fc1w, fc1b, fc2w, fc2b, out);
}